// Round 3
// baseline (923.957 us; speedup 1.0000x reference)
//
#include <hip/hip_runtime.h>
#include <math.h>

#define NWG 64

typedef __bf16 bf16x8 __attribute__((ext_vector_type(8)));
typedef float  f32x4  __attribute__((ext_vector_type(4)));

__device__ __forceinline__ float gelu_f(float x) {
  const float k0 = 0.7978845608028654f;
  const float k1 = 0.044715f;
  float x3 = x * x * x;
  return 0.5f * x * (1.0f + tanhf(k0 * (x + k1 * x3)));
}

// ---------------- mean pool over seq: (128,512,1024) -> (128,1024) bf16 ----------------
__global__ __launch_bounds__(256) void pool_kernel(
    const float* __restrict__ xe, __bf16* __restrict__ xpb) {
  int b = blockIdx.y;
  int c = blockIdx.x * 256 + threadIdx.x;
  const float* p = xe + (size_t)b * 512 * 1024 + c;
  float s = 0.f;
#pragma unroll 8
  for (int i = 0; i < 512; ++i) s += p[(size_t)i * 1024];
  xpb[b * 1024 + c] = (__bf16)(s * (1.f / 512.f));
}

// ---------------- prep: weight transposes (to N x K bf16), Wv pack, y conv, beff ----------------
__global__ __launch_bounds__(256) void prep_kernel(
    const float* __restrict__ Wpi, const float* __restrict__ Wpa,
    const float* __restrict__ Wc,  const float* __restrict__ w1f,
    const float* __restrict__ w2f, const float* __restrict__ wo,
    const float* __restrict__ wqkv, const float* __restrict__ y,
    const float* __restrict__ bqkv, const float* __restrict__ bo,
    __bf16* __restrict__ WpiT, __bf16* __restrict__ WpaT,
    __bf16* __restrict__ WcabT, __bf16* __restrict__ WccT,
    __bf16* __restrict__ w1T,  __bf16* __restrict__ w2T,
    __bf16* __restrict__ woT,  __bf16* __restrict__ Wv_b,
    __bf16* __restrict__ y_b,  float* __restrict__ beff)
{
  int bid = blockIdx.x;
  int tid = threadIdx.x;
  if (bid < 6016) {
    const float* src; __bf16* dst; int R, C;
    if      (bid < 512)  {              src = Wpi;            dst = WpiT;          R = 1024; C = 512;  }
    else if (bid < 640)  { bid -= 512;  src = Wpa;            dst = WpaT;          R = 256;  C = 512;  }
    else if (bid < 1152) { bid -= 640;  src = Wc;             dst = WcabT;         R = 1024; C = 512;  }
    else if (bid < 1408) { bid -= 1152; src = Wc + 1024*512;  dst = WccT;          R = 512;  C = 512;  }
    else if (bid < 2432) { bid -= 1408; src = w1f;            dst = w1T;           R = 512;  C = 2048; }
    else if (bid < 3456) { bid -= 2432; src = w1f + 512*2048; dst = w1T + 1048576; R = 512;  C = 2048; }
    else if (bid < 4480) { bid -= 3456; src = w2f;            dst = w2T;           R = 2048; C = 512;  }
    else if (bid < 5504) { bid -= 4480; src = w2f + 2048*512; dst = w2T + 1048576; R = 2048; C = 512;  }
    else if (bid < 5760) { bid -= 5504; src = wo;             dst = woT;           R = 512;  C = 512;  }
    else                 { bid -= 5760; src = wo + 512*512;   dst = woT + 262144;  R = 512;  C = 512;  }
    int nbc = C / 32;
    int r0 = (bid / nbc) * 32;
    int c0 = (bid % nbc) * 32;
    __shared__ float t[32][33];
    int tx = tid & 31, ty = tid >> 5;
#pragma unroll
    for (int i = 0; i < 32; i += 8)
      t[ty + i][tx] = src[(size_t)(r0 + ty + i) * C + c0 + tx];
    __syncthreads();
#pragma unroll
    for (int i = 0; i < 32; i += 8)
      dst[(size_t)(c0 + ty + i) * R + r0 + tx] = (__bf16)t[tx][ty + i];
  } else if (bid < 6272) {
    int e0 = ((bid - 6016) * 256 + tid) * 8;
    int l = e0 >> 18, rem = e0 & 262143;
    int m = rem >> 9, k = rem & 511;
    const float* s = wqkv + (size_t)l * 786432 + (size_t)m * 1536 + 1024 + k;
#pragma unroll
    for (int j = 0; j < 8; ++j) Wv_b[e0 + j] = (__bf16)s[j];
  } else if (bid < 6288) {
    int e0 = ((bid - 6272) * 256 + tid) * 8;
#pragma unroll
    for (int j = 0; j < 8; ++j) y_b[e0 + j] = (__bf16)y[e0 + j];
  } else {
    int b2 = bid - 6288;
    int l = b2 >> 1;
    int n = (b2 & 1) * 256 + tid;
    const float* bv = bqkv + l * 1536 + 1024;
    const float* w  = wo + (size_t)l * 262144;
    float s = bo[l * 512 + n];
#pragma unroll 8
    for (int k = 0; k < 512; ++k) s += bv[k] * w[(size_t)k * 512 + n];
    beff[l * 512 + n] = s;
  }
}

// ---------------- grid barrier (monotonic counter, agent scope) ----------------
__device__ __forceinline__ void gridbar(int* cnt, int target) {
  __syncthreads();   // compiler drains vmcnt before s_barrier -> WG's stores are in L2
  if (threadIdx.x == 0) {
    __hip_atomic_fetch_add(cnt, 1, __ATOMIC_RELEASE, __HIP_MEMORY_SCOPE_AGENT);
    while (__hip_atomic_load(cnt, __ATOMIC_RELAXED, __HIP_MEMORY_SCOPE_AGENT) < target) {
      __builtin_amdgcn_s_sleep(1);
    }
    __builtin_amdgcn_fence(__ATOMIC_ACQUIRE, "agent");
  }
  __syncthreads();
}

// ---------------- 64x64-tile fused GEMM (device fn, runtime flags) ----------------
// out = epi( [LN(A)] @ Bt^T ), A: MxK bf16 row-major, Bt: NxK bf16 row-major.
// Double-buffered LDS, reg-staged prefetch. resid/accumf/outf stride = 512.
__device__ __noinline__ void gemm64(
    const __bf16* __restrict__ A, const __bf16* __restrict__ Bt, int K,
    int bm0, int bn0,
    const float* __restrict__ lng, const float* __restrict__ lnb,
    const float* __restrict__ bias, const float* resid, int do_gelu,
    const float* accumf, float* outf, __bf16* __restrict__ outb,
    int ldo, int trM,
    __bf16* AL, __bf16* BL, float* smu, float* srs)
{
  const int tid = threadIdx.x;

  if (lng) {  // row LN stats: 4 threads per row
    int r = tid >> 2;
    int q = K >> 2;
    const __bf16* ap = A + (size_t)(bm0 + r) * K + (tid & 3) * q;
    float s = 0.f, s2 = 0.f;
    for (int i = 0; i < q; i += 8) {
      bf16x8 v = *(const bf16x8*)(ap + i);
#pragma unroll
      for (int j = 0; j < 8; ++j) { float f = (float)v[j]; s += f; s2 += f * f; }
    }
    s  += __shfl_xor(s, 1);  s2 += __shfl_xor(s2, 1);
    s  += __shfl_xor(s, 2);  s2 += __shfl_xor(s2, 2);
    if ((tid & 3) == 0) {
      float mu = s / (float)K;
      smu[r] = mu;
      srs[r] = rsqrtf(s2 / (float)K - mu * mu + 1e-5f);
    }
  }
  __syncthreads();  // stats visible; also guards LDS reuse across calls

  const int r0 = tid >> 3, u0 = tid & 7;
  const int r1 = r0 + 32;
  const int koff = u0 * 8;

  const int wave = tid >> 6, lane = tid & 63;
  const int wm = wave >> 1, wn = wave & 1;
  const int lr = lane & 15;
  const int lk = (lane >> 4) << 3;

  f32x4 acc00 = {}, acc01 = {}, acc10 = {}, acc11 = {};

  const int nt = K >> 6;
  const __bf16* Arow0 = A + (size_t)(bm0 + r0) * K + koff;
  const __bf16* Arow1 = A + (size_t)(bm0 + r1) * K + koff;
  const __bf16* Brow0 = Bt + (size_t)(bn0 + r0) * K + koff;
  const __bf16* Brow1 = Bt + (size_t)(bn0 + r1) * K + koff;

  bf16x8 ra0, ra1, rb0, rb1;
  f32x4 g0, g1, bb0, bb1;

  auto loadc = [&](int k0) {
    ra0 = *(const bf16x8*)(Arow0 + k0);
    ra1 = *(const bf16x8*)(Arow1 + k0);
    rb0 = *(const bf16x8*)(Brow0 + k0);
    rb1 = *(const bf16x8*)(Brow1 + k0);
    if (lng) {
      g0  = *(const f32x4*)(lng + k0 + koff);
      g1  = *(const f32x4*)(lng + k0 + koff + 4);
      bb0 = *(const f32x4*)(lnb + k0 + koff);
      bb1 = *(const f32x4*)(lnb + k0 + koff + 4);
    }
  };
  auto storec = [&](int b) {
    if (lng) {
      float m0 = smu[r0], q0 = srs[r0];
      float m1 = smu[r1], q1 = srs[r1];
#pragma unroll
      for (int j = 0; j < 4; ++j) {
        ra0[j]     = (__bf16)(((float)ra0[j]     - m0) * q0 * g0[j] + bb0[j]);
        ra0[j + 4] = (__bf16)(((float)ra0[j + 4] - m0) * q0 * g1[j] + bb1[j]);
        ra1[j]     = (__bf16)(((float)ra1[j]     - m1) * q1 * g0[j] + bb0[j]);
        ra1[j + 4] = (__bf16)(((float)ra1[j + 4] - m1) * q1 * g1[j] + bb1[j]);
      }
    }
    *(bf16x8*)(AL + b * 4608 + r0 * 72 + koff) = ra0;
    *(bf16x8*)(AL + b * 4608 + r1 * 72 + koff) = ra1;
    *(bf16x8*)(BL + b * 4608 + r0 * 72 + koff) = rb0;
    *(bf16x8*)(BL + b * 4608 + r1 * 72 + koff) = rb1;
  };

  loadc(0);
  storec(0);
  __syncthreads();

  for (int t = 0; t < nt; ++t) {
    const int b = t & 1;
    if (t + 1 < nt) loadc((t + 1) << 6);
    const __bf16* Ab = AL + b * 4608;
    const __bf16* Bb = BL + b * 4608;
#pragma unroll
    for (int kc = 0; kc < 2; ++kc) {
      bf16x8 a0 = *(const bf16x8*)(Ab + (wm * 32 + lr     ) * 72 + kc * 32 + lk);
      bf16x8 a1 = *(const bf16x8*)(Ab + (wm * 32 + 16 + lr) * 72 + kc * 32 + lk);
      bf16x8 b0 = *(const bf16x8*)(Bb + (wn * 32 + lr     ) * 72 + kc * 32 + lk);
      bf16x8 b1 = *(const bf16x8*)(Bb + (wn * 32 + 16 + lr) * 72 + kc * 32 + lk);
      acc00 = __builtin_amdgcn_mfma_f32_16x16x32_bf16(a0, b0, acc00, 0, 0, 0);
      acc01 = __builtin_amdgcn_mfma_f32_16x16x32_bf16(a0, b1, acc01, 0, 0, 0);
      acc10 = __builtin_amdgcn_mfma_f32_16x16x32_bf16(a1, b0, acc10, 0, 0, 0);
      acc11 = __builtin_amdgcn_mfma_f32_16x16x32_bf16(a1, b1, acc11, 0, 0, 0);
    }
    __syncthreads();
    if (t + 1 < nt) {
      storec(b ^ 1);
      __syncthreads();
    }
  }

  f32x4 accs[2][2] = {{acc00, acc01}, {acc10, acc11}};
#pragma unroll
  for (int mi = 0; mi < 2; ++mi)
#pragma unroll
    for (int ni = 0; ni < 2; ++ni)
#pragma unroll
      for (int e = 0; e < 4; ++e) {
        int row = bm0 + wm * 32 + mi * 16 + ((lane >> 4) << 2) + e;
        int col = bn0 + wn * 32 + ni * 16 + lr;
        float v = accs[mi][ni][e];
        if (bias)    v += bias[col];
        if (resid)   v += resid[(size_t)row * 512 + col];
        if (do_gelu) v = gelu_f(v);
        if (accumf)  v += accumf[(size_t)row * 512 + col];
        if (outf)    outf[(size_t)row * 512 + col] = v;
        if (outb) {
          if (trM) outb[(size_t)col * trM + row] = (__bf16)v;
          else     outb[(size_t)row * ldo + col] = (__bf16)v;
        }
      }
}

// ---------------- persistent mega kernel: Weff, projections, base, 6-rec chain ----------------
__global__ __launch_bounds__(256) void mega_kernel(
    const __bf16* xp_b, const __bf16* y_b,
    const __bf16* WpiT, const __bf16* WpaT, const __bf16* WcabT, const __bf16* WccT,
    const __bf16* w1T, const __bf16* w2T, const __bf16* woT, const __bf16* Wv_b,
    const float* bpi, const float* bpa, const float* bc,
    const float* ln1g, const float* ln1b, const float* ln2g, const float* ln2b,
    const float* b1f, const float* b2f, const float* beff_,
    __bf16* WeffT, __bf16* xy_b, float* base_f, float* c_f, __bf16* c_b,
    float* x_f, __bf16* xb0, __bf16* xb1, __bf16* u_b,
    float* z_f, __bf16* z_b, float* out, int* bcnt)
{
  __shared__ __bf16 AL[2 * 64 * 72];
  __shared__ __bf16 BL[2 * 64 * 72];
  __shared__ float smu[64], srs[64];
  const int wg = blockIdx.x;
  const int tid = threadIdx.x;
  int bar = 0;

  // stage A: WeffT[l] = (Wv[l] @ wo[l])^T  (2 jobs per WG)
  for (int j = wg; j < 128; j += NWG) {
    int l = j >> 6, t = j & 63;
    gemm64(Wv_b + l * 262144, woT + l * 262144, 512, (t >> 3) * 64, (t & 7) * 64,
           nullptr, nullptr, nullptr, nullptr, 0, nullptr, nullptr,
           WeffT + l * 262144, 0, 512, AL, BL, smu, srs);
  }
  gridbar(bcnt, bar += NWG);

  // stage B: xy = [x_pooled@Wpi+bpi | y@Wpa+bpa]; idle WGs zero z
  if (wg < 16) {
    gemm64(xp_b, WpiT, 1024, (wg >> 3) * 64, (wg & 7) * 64,
           nullptr, nullptr, bpi, nullptr, 0, nullptr, nullptr,
           xy_b, 1024, 0, AL, BL, smu, srs);
  } else if (wg < 32) {
    int j = wg - 16;
    gemm64(y_b, WpaT, 256, (j >> 3) * 64, (j & 7) * 64,
           nullptr, nullptr, bpa, nullptr, 0, nullptr, nullptr,
           xy_b + 512, 1024, 0, AL, BL, smu, srs);
  } else {
    int base = (wg - 32) * 2048 + tid * 8;
#pragma unroll
    for (int j = 0; j < 8; ++j) z_f[base + j] = 0.f;
#pragma unroll
    for (int j = 0; j < 8; ++j) z_b[base + j] = (__bf16)0.f;
  }
  gridbar(bcnt, bar += NWG);

  // stage C: base = xy @ Wcab + bc ; c_b = bf16(base) for r=0
  if (wg < 16) {
    gemm64(xy_b, WcabT, 1024, (wg >> 3) * 64, (wg & 7) * 64,
           nullptr, nullptr, bc, nullptr, 0, nullptr,
           base_f, c_b, 512, 0, AL, BL, smu, srs);
  }
  gridbar(bcnt, bar += NWG);

  for (int r = 0; r < 6; ++r) {
    if (r > 0) {  // S1: c = base + z @ Wcc
      if (wg < 16) {
        gemm64(z_b, WccT, 512, (wg >> 3) * 64, (wg & 7) * 64,
               nullptr, nullptr, nullptr, base_f, 0, nullptr,
               c_f, c_b, 512, 0, AL, BL, smu, srs);
      }
      gridbar(bcnt, bar += NWG);
    }
    const float* base_or_c = (r > 0) ? c_f : base_f;
    for (int l = 0; l < 2; ++l) {
      const __bf16* Ain = (l == 0) ? c_b : xb1;
      const float*  Rin = (l == 0) ? base_or_c : x_f;
      // S2: x = resid + LN1(A) @ Weff + beff
      if (wg < 16) {
        gemm64(Ain, WeffT + l * 262144, 512, (wg >> 3) * 64, (wg & 7) * 64,
               ln1g + l * 512, ln1b + l * 512, beff_ + l * 512, Rin, 0, nullptr,
               x_f, xb0, 512, 0, AL, BL, smu, srs);
      }
      gridbar(bcnt, bar += NWG);
      // S3: u = gelu(LN2(x) @ w1 + b1)   (64 jobs, all WGs)
      gemm64(xb0, w1T + l * 1048576, 512, (wg >> 5) * 64, (wg & 31) * 64,
             ln2g + l * 512, ln2b + l * 512, b1f + l * 2048, nullptr, 1, nullptr,
             nullptr, u_b, 2048, 0, AL, BL, smu, srs);
      gridbar(bcnt, bar += NWG);
      // S4: x = x + u @ w2 + b2 ; on l==1 accumulate into z (r==5 -> d_out)
      if (wg < 16) {
        if (l == 0) {
          gemm64(u_b, w2T + l * 1048576, 2048, (wg >> 3) * 64, (wg & 7) * 64,
                 nullptr, nullptr, b2f + l * 512, x_f, 0, nullptr,
                 x_f, xb1, 512, 0, AL, BL, smu, srs);
        } else if (r < 5) {
          gemm64(u_b, w2T + l * 1048576, 2048, (wg >> 3) * 64, (wg & 7) * 64,
                 nullptr, nullptr, b2f + l * 512, x_f, 0, z_f,
                 z_f, z_b, 512, 0, AL, BL, smu, srs);
        } else {
          gemm64(u_b, w2T + l * 1048576, 2048, (wg >> 3) * 64, (wg & 7) * 64,
                 nullptr, nullptr, b2f + l * 512, x_f, 0, z_f,
                 out, nullptr, 512, 0, AL, BL, smu, srs);
        }
      }
      if (!(r == 5 && l == 1)) gridbar(bcnt, bar += NWG);
    }
  }
}

extern "C" void kernel_launch(void* const* d_in, const int* in_sizes, int n_in,
                              void* d_out, int out_size, void* d_ws, size_t ws_size,
                              hipStream_t stream) {
  const float* x_encoded = (const float*)d_in[0];
  const float* y_current = (const float*)d_in[1];
  const float* Wpi  = (const float*)d_in[2];
  const float* bpi  = (const float*)d_in[3];
  const float* Wpa  = (const float*)d_in[4];
  const float* bpa  = (const float*)d_in[5];
  const float* Wc   = (const float*)d_in[6];
  const float* bc   = (const float*)d_in[7];
  const float* ln1g = (const float*)d_in[8];
  const float* ln1b = (const float*)d_in[9];
  const float* wqkv = (const float*)d_in[10];
  const float* bqkv = (const float*)d_in[11];
  const float* wo   = (const float*)d_in[12];
  const float* bo   = (const float*)d_in[13];
  const float* ln2g = (const float*)d_in[14];
  const float* ln2b = (const float*)d_in[15];
  const float* w1f  = (const float*)d_in[16];
  const float* b1f  = (const float*)d_in[17];
  const float* w2f  = (const float*)d_in[18];
  const float* b2f  = (const float*)d_in[19];
  (void)in_sizes; (void)n_in; (void)out_size; (void)ws_size;

  char* wsb = (char*)d_ws;
  size_t off = 0;
  auto carve = [&](size_t bytes) -> void* {
    void* p = wsb + off;
    off += (bytes + 255) & ~(size_t)255;
    return p;
  };
  __bf16* xp_b    = (__bf16*)carve(131072 * 2);
  __bf16* y_b     = (__bf16*)carve(32768 * 2);
  __bf16* WpiT    = (__bf16*)carve(524288 * 2);
  __bf16* WpaT    = (__bf16*)carve(131072 * 2);
  __bf16* WcabT   = (__bf16*)carve(524288 * 2);
  __bf16* WccT    = (__bf16*)carve(262144 * 2);
  __bf16* w1T     = (__bf16*)carve(2097152 * 2);
  __bf16* w2T     = (__bf16*)carve(2097152 * 2);
  __bf16* woT     = (__bf16*)carve(524288 * 2);
  __bf16* Wv_b    = (__bf16*)carve(524288 * 2);
  __bf16* WeffT   = (__bf16*)carve(524288 * 2);
  float*  beff    = (float*) carve(1024 * 4);
  __bf16* xy_b    = (__bf16*)carve(131072 * 2);
  float*  base_f  = (float*) carve(65536 * 4);
  float*  c_f     = (float*) carve(65536 * 4);
  __bf16* c_b     = (__bf16*)carve(65536 * 2);
  float*  x_f     = (float*) carve(65536 * 4);
  __bf16* xb0     = (__bf16*)carve(65536 * 2);
  __bf16* xb1     = (__bf16*)carve(65536 * 2);
  __bf16* u_b     = (__bf16*)carve(262144 * 2);
  float*  z_f     = (float*) carve(65536 * 4);
  __bf16* z_b     = (__bf16*)carve(65536 * 2);
  int*    d_bar   = (int*)   carve(256);

  hipMemsetAsync(d_bar, 0, 256, stream);
  pool_kernel<<<dim3(4, 128), 256, 0, stream>>>(x_encoded, xp_b);
  prep_kernel<<<6292, 256, 0, stream>>>(Wpi, Wpa, Wc, w1f, w2f, wo, wqkv, y_current,
      bqkv, bo, WpiT, WpaT, WcabT, WccT, w1T, w2T, woT, Wv_b, y_b, beff);
  mega_kernel<<<NWG, 256, 0, stream>>>(
      xp_b, y_b, WpiT, WpaT, WcabT, WccT, w1T, w2T, woT, Wv_b,
      bpi, bpa, bc, ln1g, ln1b, ln2g, ln2b, b1f, b2f, beff,
      WeffT, xy_b, base_f, c_f, c_b, x_f, xb0, xb1, u_b,
      z_f, z_b, (float*)d_out, d_bar);
}

// Round 4
// 551.124 us; speedup vs baseline: 1.6765x; 1.6765x over previous
//
#include <hip/hip_runtime.h>
#include <math.h>

#define NWG 64

typedef __bf16 bf16x8 __attribute__((ext_vector_type(8)));
typedef __bf16 bf16x4 __attribute__((ext_vector_type(4)));
typedef float  f32x4  __attribute__((ext_vector_type(4)));
typedef unsigned long long u64;

__device__ __forceinline__ float gelu_f(float x) {
  const float k0 = 0.7978845608028654f;
  const float k1 = 0.044715f;
  float x3 = x * x * x;
  return 0.5f * x * (1.0f + tanhf(k0 * (x + k1 * x3)));
}

// coherent (agent-scope, IF$-backed) accessors: bypass non-coherent per-XCD L2
__device__ __forceinline__ u64 cload8(const void* p) {
  return __hip_atomic_load((u64*)p, __ATOMIC_RELAXED, __HIP_MEMORY_SCOPE_AGENT);
}
__device__ __forceinline__ void cstore_bf16(__bf16* p, __bf16 h) {
  __hip_atomic_store((short*)p, __builtin_bit_cast(short, h),
                     __ATOMIC_RELAXED, __HIP_MEMORY_SCOPE_AGENT);
}

// ---------------- prep: pool + weight transposes + Wv pack + y conv + beff ----------------
__global__ __launch_bounds__(256) void prep_kernel(
    const float* __restrict__ xe,
    const float* __restrict__ Wpi, const float* __restrict__ Wpa,
    const float* __restrict__ Wc,  const float* __restrict__ w1f,
    const float* __restrict__ w2f, const float* __restrict__ wo,
    const float* __restrict__ wqkv, const float* __restrict__ y,
    const float* __restrict__ bqkv, const float* __restrict__ bo,
    __bf16* __restrict__ xp_b,
    __bf16* __restrict__ WpiT, __bf16* __restrict__ WpaT,
    __bf16* __restrict__ WcabT, __bf16* __restrict__ WccT,
    __bf16* __restrict__ w1T,  __bf16* __restrict__ w2T,
    __bf16* __restrict__ woT,  __bf16* __restrict__ Wv_b,
    __bf16* __restrict__ y_b,  float* __restrict__ beff)
{
  int bid = blockIdx.x;
  int tid = threadIdx.x;
  if (bid < 512) {               // mean pool (128,512,1024) -> (128,1024) bf16
    int b = bid >> 2;
    int c = (bid & 3) * 256 + tid;
    const float* p = xe + (size_t)b * 512 * 1024 + c;
    float s = 0.f;
#pragma unroll 16
    for (int i = 0; i < 512; ++i) s += p[(size_t)i * 1024];
    xp_b[b * 1024 + c] = (__bf16)(s * (1.f / 512.f));
  } else if (bid < 6528) {       // transposes fp32 -> bf16 (N x K layout)
    int t = bid - 512;
    const float* src; __bf16* dst; int R, C;
    if      (t < 512)  {            src = Wpi;            dst = WpiT;          R = 1024; C = 512;  }
    else if (t < 640)  { t -= 512;  src = Wpa;            dst = WpaT;          R = 256;  C = 512;  }
    else if (t < 1152) { t -= 640;  src = Wc;             dst = WcabT;         R = 1024; C = 512;  }
    else if (t < 1408) { t -= 1152; src = Wc + 1024*512;  dst = WccT;          R = 512;  C = 512;  }
    else if (t < 2432) { t -= 1408; src = w1f;            dst = w1T;           R = 512;  C = 2048; }
    else if (t < 3456) { t -= 2432; src = w1f + 512*2048; dst = w1T + 1048576; R = 512;  C = 2048; }
    else if (t < 4480) { t -= 3456; src = w2f;            dst = w2T;           R = 2048; C = 512;  }
    else if (t < 5504) { t -= 4480; src = w2f + 2048*512; dst = w2T + 1048576; R = 2048; C = 512;  }
    else if (t < 5760) { t -= 5504; src = wo;             dst = woT;           R = 512;  C = 512;  }
    else               { t -= 5760; src = wo + 512*512;   dst = woT + 262144;  R = 512;  C = 512;  }
    int nbc = C / 32;
    int r0 = (t / nbc) * 32;
    int c0 = (t % nbc) * 32;
    __shared__ float tt[32][33];
    int tx = tid & 31, ty = tid >> 5;
#pragma unroll
    for (int i = 0; i < 32; i += 8)
      tt[ty + i][tx] = src[(size_t)(r0 + ty + i) * C + c0 + tx];
    __syncthreads();
#pragma unroll
    for (int i = 0; i < 32; i += 8)
      dst[(size_t)(c0 + ty + i) * R + r0 + tx] = (__bf16)tt[tx][ty + i];
  } else if (bid < 6784) {       // Wv pack: Wv_b[l][j][m] = wqkv[l][j][1024+m]
    int e0 = ((bid - 6528) * 256 + tid) * 8;
    int l = e0 >> 18, rem = e0 & 262143;
    int m = rem >> 9, k = rem & 511;
    const float* s = wqkv + (size_t)l * 786432 + (size_t)m * 1536 + 1024 + k;
#pragma unroll
    for (int j = 0; j < 8; ++j) Wv_b[e0 + j] = (__bf16)s[j];
  } else if (bid < 6800) {       // y -> bf16
    int e0 = ((bid - 6784) * 256 + tid) * 8;
#pragma unroll
    for (int j = 0; j < 8; ++j) y_b[e0 + j] = (__bf16)y[e0 + j];
  } else {                       // beff[l] = bv @ wo + bo
    int b2 = bid - 6800;
    int l = b2 >> 1;
    int n = (b2 & 1) * 256 + tid;
    const float* bv = bqkv + l * 1536 + 1024;
    const float* w  = wo + (size_t)l * 262144;
    float s = bo[l * 512 + n];
#pragma unroll 8
    for (int k = 0; k < 512; ++k) s += bv[k] * w[(size_t)k * 512 + n];
    beff[l * 512 + n] = s;
  }
}

// ---------------- fence-free grid barrier (relaxed atomics only; no L2 inv/wb) ----------------
__device__ __forceinline__ void gridbar(int* cnt, int target) {
  asm volatile("s_waitcnt vmcnt(0)" ::: "memory");
  __syncthreads();
  if (threadIdx.x == 0) {
    __hip_atomic_fetch_add(cnt, 1, __ATOMIC_RELAXED, __HIP_MEMORY_SCOPE_AGENT);
    while (__hip_atomic_load(cnt, __ATOMIC_RELAXED, __HIP_MEMORY_SCOPE_AGENT) < target)
      __builtin_amdgcn_s_sleep(2);
  }
  __syncthreads();
  asm volatile("" ::: "memory");
}

// ---------------- LN row stats (row = tid>>3, 8 threads/row) ----------------
template<int NT, bool COHA>
__device__ __forceinline__ void ln_stats(const __bf16* A, int bm0, float& mu, float& rsg) {
  const int K = NT * 64;
  const int tid = threadIdx.x;
  const int row = tid >> 3, j8 = tid & 7;
  const __bf16* ap = A + (size_t)(bm0 + row) * K + j8 * (K / 8);
  float s = 0.f, s2 = 0.f;
#pragma unroll
  for (int i = 0; i < K / 8; i += 4) {
    bf16x4 v;
    if (COHA) v = __builtin_bit_cast(bf16x4, cload8(ap + i));
    else      v = *(const bf16x4*)(ap + i);
#pragma unroll
    for (int j = 0; j < 4; ++j) { float f = (float)v[j]; s += f; s2 += f * f; }
  }
  s  += __shfl_xor(s, 1);  s2 += __shfl_xor(s2, 1);
  s  += __shfl_xor(s, 2);  s2 += __shfl_xor(s2, 2);
  s  += __shfl_xor(s, 4);  s2 += __shfl_xor(s2, 4);
  mu = s / (float)K;
  rsg = rsqrtf(s2 / (float)K - mu * mu + 1e-5f);
}

// ---------------- 32x32-tile fused GEMM, depth-4 register pipeline ----------------
// out = epi( [LN(A)] @ Bt^T ); A: Mx(NT*64) row-major, Bt: Nx(NT*64) row-major.
// LNMODE: 0 none, 1 compute stats, 2 use mu_in/rs_in. resid/accum/outf stride 512.
template<int NT, int LNMODE, bool GELU, bool COHA, bool BIAS, bool RESID,
         bool ACCUM, bool OUTF, bool OUTB, bool COHO>
__device__ __forceinline__ void gemm32(
    const __bf16* A, const __bf16* Bt, int bm0, int bn0,
    const float* lng, const float* lnb, const float* bias,
    const float* resid, const float* accum, float* outf, __bf16* outb, int ldo,
    __bf16* AL, __bf16* BL, float mu_in = 0.f, float rs_in = 0.f)
{
  const int tid = threadIdx.x;
  constexpr int K = NT * 64;
  const int row = tid >> 3;
  const int kcol = (tid & 7) * 8;

  float mu = mu_in, rsg = rs_in;
  if (LNMODE == 1) ln_stats<NT, COHA>(A, bm0, mu, rsg);

  const __bf16* Ab0 = A + (size_t)(bm0 + row) * K + kcol;
  const __bf16* Bb0 = Bt + (size_t)(bn0 + row) * K + kcol;

  u64 ra0[4], ra1[4], rb0[4], rb1[4];
  auto issue = [&](int t, int s) {
    const __bf16* ap = Ab0 + t * 64;
    const __bf16* bp = Bb0 + t * 64;
    if (COHA) { ra0[s] = cload8(ap); ra1[s] = cload8(ap + 4); }
    else      { ra0[s] = *(const u64*)ap; ra1[s] = *(const u64*)(ap + 4); }
    rb0[s] = *(const u64*)bp; rb1[s] = *(const u64*)(bp + 4);
  };
#pragma unroll
  for (int s = 0; s < 4; ++s) issue(s, s);

  f32x4 acc = {0.f, 0.f, 0.f, 0.f};
  const int wave = tid >> 6, lane = tid & 63;
  const int wr = (wave >> 1) * 16, wc = (wave & 1) * 16;
  const int lr = lane & 15, lk8 = (lane >> 4) * 8;

  for (int ttc = 0; ttc < NT / 4; ++ttc) {
#pragma unroll
    for (int ti = 0; ti < 4; ++ti) {
      const int t = ttc * 4 + ti;
      bf16x4 lo = __builtin_bit_cast(bf16x4, ra0[ti]);
      bf16x4 hi = __builtin_bit_cast(bf16x4, ra1[ti]);
      if (LNMODE != 0) {
        const int kb = t * 64 + kcol;
        f32x4 g0 = *(const f32x4*)(lng + kb);
        f32x4 g1 = *(const f32x4*)(lng + kb + 4);
        f32x4 b0 = *(const f32x4*)(lnb + kb);
        f32x4 b1 = *(const f32x4*)(lnb + kb + 4);
#pragma unroll
        for (int j = 0; j < 4; ++j) {
          lo[j] = (__bf16)(((float)lo[j] - mu) * rsg * g0[j] + b0[j]);
          hi[j] = (__bf16)(((float)hi[j] - mu) * rsg * g1[j] + b1[j]);
        }
      }
      __bf16* al = AL + (ti & 1) * 2304 + row * 72 + kcol;
      __bf16* bl = BL + (ti & 1) * 2304 + row * 72 + kcol;
      *(bf16x4*)al = lo; *(bf16x4*)(al + 4) = hi;
      *(bf16x4*)bl = __builtin_bit_cast(bf16x4, rb0[ti]);
      *(bf16x4*)(bl + 4) = __builtin_bit_cast(bf16x4, rb1[ti]);
      __syncthreads();
      if (t + 4 < NT) issue(t + 4, ti);
      const __bf16* Ar = AL + (ti & 1) * 2304 + (wr + lr) * 72;
      const __bf16* Br = BL + (ti & 1) * 2304 + (wc + lr) * 72;
      bf16x8 a0 = *(const bf16x8*)(Ar + lk8);
      bf16x8 b0v = *(const bf16x8*)(Br + lk8);
      acc = __builtin_amdgcn_mfma_f32_16x16x32_bf16(a0, b0v, acc, 0, 0, 0);
      bf16x8 a1 = *(const bf16x8*)(Ar + 32 + lk8);
      bf16x8 b1v = *(const bf16x8*)(Br + 32 + lk8);
      acc = __builtin_amdgcn_mfma_f32_16x16x32_bf16(a1, b1v, acc, 0, 0, 0);
      __syncthreads();
    }
  }

  const int er = bm0 + wr + (lane >> 4) * 4;
  const int ec = bn0 + wc + lr;
#pragma unroll
  for (int e = 0; e < 4; ++e) {
    const int r = er + e;
    float v = acc[e];
    if (BIAS)  v += bias[ec];
    if (RESID) v += resid[r * 512 + ec];
    if (GELU)  v = gelu_f(v);
    if (ACCUM) v += accum[r * 512 + ec];
    if (OUTF)  outf[r * 512 + ec] = v;
    if (OUTB) {
      __bf16 h = (__bf16)v;
      if (COHO) cstore_bf16(outb + (size_t)r * ldo + ec, h);
      else      outb[(size_t)r * ldo + ec] = h;
    }
  }
}

// ---------------- aux: Weff GEMMs + projections (one-shot, normal caching) ----------------
__global__ __launch_bounds__(256) void aux_kernel(
    const __bf16* __restrict__ woT, const __bf16* __restrict__ Wv_b,
    const __bf16* __restrict__ xp_b, const __bf16* __restrict__ y_b,
    const __bf16* __restrict__ WpiT, const __bf16* __restrict__ WpaT,
    const float* __restrict__ bpi, const float* __restrict__ bpa,
    __bf16* __restrict__ WeffT, __bf16* __restrict__ xy_b)
{
  __shared__ __bf16 AL[2 * 32 * 72];
  __shared__ __bf16 BL[2 * 32 * 72];
  int bid = blockIdx.x;
  if (bid < 512) {        // WeffT[l][n][j] = sum_m woT[l][n][m] * Wv_b[l][j][m]
    int l = bid >> 8, t = bid & 255;
    gemm32<8,0,0,0,0,0,0,0,1,0>(woT + l * 262144, Wv_b + l * 262144,
        (t >> 4) * 32, (t & 15) * 32, nullptr, nullptr, nullptr,
        nullptr, nullptr, nullptr, WeffT + l * 262144, 512, AL, BL);
  } else if (bid < 576) { // xy[:, :512] = xp @ Wpi + bpi
    int t = bid - 512;
    gemm32<16,0,0,0,1,0,0,0,1,0>(xp_b, WpiT, (t >> 4) * 32, (t & 15) * 32,
        nullptr, nullptr, bpi, nullptr, nullptr, nullptr, xy_b, 1024, AL, BL);
  } else {                // xy[:, 512:] = y @ Wpa + bpa
    int t = bid - 576;
    gemm32<4,0,0,0,1,0,0,0,1,0>(y_b, WpaT, (t >> 4) * 32, (t & 15) * 32,
        nullptr, nullptr, bpa, nullptr, nullptr, nullptr, xy_b + 512, 1024, AL, BL);
  }
}

// ---------------- persistent mega kernel: base + 6-rec chain ----------------
__global__ __launch_bounds__(256) void mega_kernel(
    const __bf16* __restrict__ xy_b, const __bf16* __restrict__ WcabT,
    const __bf16* __restrict__ WccT, const __bf16* __restrict__ WeffT,
    const __bf16* __restrict__ w1T, const __bf16* __restrict__ w2T,
    const float* __restrict__ bc, const float* __restrict__ beff,
    const float* __restrict__ ln1g, const float* __restrict__ ln1b,
    const float* __restrict__ ln2g, const float* __restrict__ ln2b,
    const float* __restrict__ b1f, const float* __restrict__ b2f,
    float* base_f, float* c_f, __bf16* c_b, float* x_f,
    __bf16* xb2, __bf16* xb4, __bf16* u_b, float* z_f, __bf16* z_b,
    float* out, int* bcnt)
{
  __shared__ __bf16 AL[2 * 32 * 72];
  __shared__ __bf16 BL[2 * 32 * 72];
  const int wg = blockIdx.x;
  const int xcd = wg & 7, slot = wg >> 3;
  const int bm = (slot & 3) * 32;
  const int bn = (((xcd << 1) | (slot >> 2))) * 32;
  int bar = 0;

  // base = xy @ Wcab + bc  (writes f32 base + coherent bf16 c_b for r=0)
  gemm32<16,0,0,0,1,0,0,1,1,1>(xy_b, WcabT, bm, bn, nullptr, nullptr, bc,
      nullptr, nullptr, base_f, c_b, 512, AL, BL);
  gridbar(bcnt, bar += NWG);

  for (int r = 0; r < 6; ++r) {
    if (r > 0) {  // S1: c = base + z @ Wcc
      gemm32<8,0,0,1,0,1,0,1,1,1>(z_b, WccT, bm, bn, nullptr, nullptr, nullptr,
          base_f, nullptr, c_f, c_b, 512, AL, BL);
      gridbar(bcnt, bar += NWG);
    }
    for (int l = 0; l < 2; ++l) {
      const __bf16* Ain = (l == 0) ? c_b : xb4;
      const float*  Rin = (l == 0) ? ((r > 0) ? c_f : base_f) : x_f;
      // S2: x = resid + LN1(A) @ Weff + beff
      gemm32<8,1,0,1,1,1,0,1,1,1>(Ain, WeffT + l * 262144, bm, bn,
          ln1g + l * 512, ln1b + l * 512, beff + l * 512, Rin, nullptr,
          x_f, xb2, 512, AL, BL);
      gridbar(bcnt, bar += NWG);
      // S3: u = gelu(LN2(x) @ w1 + b1)  — stats once, 4 n-tiles per WG
      {
        float mu, rsg;
        ln_stats<8, true>(xb2, bm, mu, rsg);
        for (int i = 0; i < 4; ++i) {
          int n3 = (xcd << 3) | ((slot >> 2) << 2) | i;
          gemm32<8,2,1,1,1,0,0,0,1,1>(xb2, w1T + l * 1048576, bm, n3 * 32,
              ln2g + l * 512, ln2b + l * 512, b1f + l * 2048, nullptr, nullptr,
              nullptr, u_b, 2048, AL, BL, mu, rsg);
        }
      }
      gridbar(bcnt, bar += NWG);
      // S4: x = x + u @ w2 + b2 ; layer 1 accumulates into z (r=5 -> d_out)
      if (l == 0) {
        gemm32<32,0,0,1,1,1,0,1,1,1>(u_b, w2T, bm, bn, nullptr, nullptr, b2f,
            x_f, nullptr, x_f, xb4, 512, AL, BL);
        gridbar(bcnt, bar += NWG);
      } else {
        if (r == 0) {
          gemm32<32,0,0,1,1,1,0,1,1,1>(u_b, w2T + 1048576, bm, bn, nullptr, nullptr,
              b2f + 512, x_f, nullptr, z_f, z_b, 512, AL, BL);
        } else if (r < 5) {
          gemm32<32,0,0,1,1,1,1,1,1,1>(u_b, w2T + 1048576, bm, bn, nullptr, nullptr,
              b2f + 512, x_f, z_f, z_f, z_b, 512, AL, BL);
        } else {
          gemm32<32,0,0,1,1,1,1,1,0,0>(u_b, w2T + 1048576, bm, bn, nullptr, nullptr,
              b2f + 512, x_f, z_f, out, nullptr, 512, AL, BL);
        }
        if (r < 5) gridbar(bcnt, bar += NWG);
      }
    }
  }
}

extern "C" void kernel_launch(void* const* d_in, const int* in_sizes, int n_in,
                              void* d_out, int out_size, void* d_ws, size_t ws_size,
                              hipStream_t stream) {
  const float* x_encoded = (const float*)d_in[0];
  const float* y_current = (const float*)d_in[1];
  const float* Wpi  = (const float*)d_in[2];
  const float* bpi  = (const float*)d_in[3];
  const float* Wpa  = (const float*)d_in[4];
  const float* bpa  = (const float*)d_in[5];
  const float* Wc   = (const float*)d_in[6];
  const float* bc   = (const float*)d_in[7];
  const float* ln1g = (const float*)d_in[8];
  const float* ln1b = (const float*)d_in[9];
  const float* wqkv = (const float*)d_in[10];
  const float* bqkv = (const float*)d_in[11];
  const float* wo   = (const float*)d_in[12];
  const float* bo   = (const float*)d_in[13];
  const float* ln2g = (const float*)d_in[14];
  const float* ln2b = (const float*)d_in[15];
  const float* w1f  = (const float*)d_in[16];
  const float* b1f  = (const float*)d_in[17];
  const float* w2f  = (const float*)d_in[18];
  const float* b2f  = (const float*)d_in[19];
  (void)in_sizes; (void)n_in; (void)out_size; (void)ws_size;

  char* wsb = (char*)d_ws;
  size_t off = 0;
  auto carve = [&](size_t bytes) -> void* {
    void* p = wsb + off;
    off += (bytes + 255) & ~(size_t)255;
    return p;
  };
  __bf16* xp_b    = (__bf16*)carve(131072 * 2);
  __bf16* y_b     = (__bf16*)carve(32768 * 2);
  __bf16* WpiT    = (__bf16*)carve(524288 * 2);
  __bf16* WpaT    = (__bf16*)carve(131072 * 2);
  __bf16* WcabT   = (__bf16*)carve(524288 * 2);
  __bf16* WccT    = (__bf16*)carve(262144 * 2);
  __bf16* w1T     = (__bf16*)carve(2097152 * 2);
  __bf16* w2T     = (__bf16*)carve(2097152 * 2);
  __bf16* woT     = (__bf16*)carve(524288 * 2);
  __bf16* Wv_b    = (__bf16*)carve(524288 * 2);
  __bf16* WeffT   = (__bf16*)carve(524288 * 2);
  float*  beff    = (float*) carve(1024 * 4);
  __bf16* xy_b    = (__bf16*)carve(131072 * 2);
  float*  base_f  = (float*) carve(65536 * 4);
  float*  c_f     = (float*) carve(65536 * 4);
  __bf16* c_b     = (__bf16*)carve(65536 * 2);
  float*  x_f     = (float*) carve(65536 * 4);
  __bf16* xb2     = (__bf16*)carve(65536 * 2);
  __bf16* xb4     = (__bf16*)carve(65536 * 2);
  __bf16* u_b     = (__bf16*)carve(262144 * 2);
  float*  z_f     = (float*) carve(65536 * 4);
  __bf16* z_b     = (__bf16*)carve(65536 * 2);
  int*    d_bar   = (int*)   carve(256);

  hipMemsetAsync(d_bar, 0, 256, stream);
  prep_kernel<<<6804, 256, 0, stream>>>(x_encoded, Wpi, Wpa, Wc, w1f, w2f, wo,
      wqkv, y_current, bqkv, bo, xp_b, WpiT, WpaT, WcabT, WccT, w1T, w2T, woT,
      Wv_b, y_b, beff);
  aux_kernel<<<640, 256, 0, stream>>>(woT, Wv_b, xp_b, y_b, WpiT, WpaT,
      bpi, bpa, WeffT, xy_b);
  mega_kernel<<<NWG, 256, 0, stream>>>(
      xy_b, WcabT, WccT, WeffT, w1T, w2T, bc, beff,
      ln1g, ln1b, ln2g, ln2b, b1f, b2f,
      base_f, c_f, c_b, x_f, xb2, xb4, u_b, z_f, z_b,
      (float*)d_out, d_bar);
}

// Round 5
// 550.612 us; speedup vs baseline: 1.6781x; 1.0009x over previous
//
#include <hip/hip_runtime.h>
#include <math.h>

#define NWG 64

typedef __bf16 bf16x8 __attribute__((ext_vector_type(8)));
typedef __bf16 bf16x4 __attribute__((ext_vector_type(4)));
typedef float  f32x4  __attribute__((ext_vector_type(4)));
typedef unsigned long long u64;

__device__ __forceinline__ float gelu_f(float x) {
  const float k0 = 0.7978845608028654f;
  const float k1 = 0.044715f;
  float x3 = x * x * x;
  return 0.5f * x * (1.0f + tanhf(k0 * (x + k1 * x3)));
}

// coherent (agent-scope, IF$-backed) accessors: bypass non-coherent per-XCD L2
__device__ __forceinline__ u64 cload8(const void* p) {
  return __hip_atomic_load((u64*)p, __ATOMIC_RELAXED, __HIP_MEMORY_SCOPE_AGENT);
}
__device__ __forceinline__ void cstore_bf16(__bf16* p, __bf16 h) {
  __hip_atomic_store((short*)p, __builtin_bit_cast(short, h),
                     __ATOMIC_RELAXED, __HIP_MEMORY_SCOPE_AGENT);
}

// ---------------- prep: pool + weight transposes + Wv pack + y conv + beff ----------------
__global__ __launch_bounds__(256) void prep_kernel(
    const float* __restrict__ xe,
    const float* __restrict__ Wpi, const float* __restrict__ Wpa,
    const float* __restrict__ Wc,  const float* __restrict__ w1f,
    const float* __restrict__ w2f, const float* __restrict__ wo,
    const float* __restrict__ wqkv, const float* __restrict__ y,
    const float* __restrict__ bqkv, const float* __restrict__ bo,
    __bf16* __restrict__ xp_b,
    __bf16* __restrict__ WpiT, __bf16* __restrict__ WpaT,
    __bf16* __restrict__ WcabT, __bf16* __restrict__ WccT,
    __bf16* __restrict__ w1T,  __bf16* __restrict__ w2T,
    __bf16* __restrict__ woT,  __bf16* __restrict__ Wv_b,
    __bf16* __restrict__ y_b,  float* __restrict__ beff)
{
  int bid = blockIdx.x;
  int tid = threadIdx.x;
  if (bid < 512) {               // mean pool (128,512,1024) -> (128,1024) bf16
    int b = bid >> 2;
    int c = (bid & 3) * 256 + tid;
    const float* p = xe + (size_t)b * 512 * 1024 + c;
    float s = 0.f;
#pragma unroll 16
    for (int i = 0; i < 512; ++i) s += p[(size_t)i * 1024];
    xp_b[b * 1024 + c] = (__bf16)(s * (1.f / 512.f));
  } else if (bid < 6528) {       // transposes fp32 -> bf16 (N x K layout)
    int t = bid - 512;
    const float* src; __bf16* dst; int R, C;
    if      (t < 512)  {            src = Wpi;            dst = WpiT;          R = 1024; C = 512;  }
    else if (t < 640)  { t -= 512;  src = Wpa;            dst = WpaT;          R = 256;  C = 512;  }
    else if (t < 1152) { t -= 640;  src = Wc;             dst = WcabT;         R = 1024; C = 512;  }
    else if (t < 1408) { t -= 1152; src = Wc + 1024*512;  dst = WccT;          R = 512;  C = 512;  }
    else if (t < 2432) { t -= 1408; src = w1f;            dst = w1T;           R = 512;  C = 2048; }
    else if (t < 3456) { t -= 2432; src = w1f + 512*2048; dst = w1T + 1048576; R = 512;  C = 2048; }
    else if (t < 4480) { t -= 3456; src = w2f;            dst = w2T;           R = 2048; C = 512;  }
    else if (t < 5504) { t -= 4480; src = w2f + 2048*512; dst = w2T + 1048576; R = 2048; C = 512;  }
    else if (t < 5760) { t -= 5504; src = wo;             dst = woT;           R = 512;  C = 512;  }
    else               { t -= 5760; src = wo + 512*512;   dst = woT + 262144;  R = 512;  C = 512;  }
    int nbc = C / 32;
    int r0 = (t / nbc) * 32;
    int c0 = (t % nbc) * 32;
    __shared__ float tt[32][33];
    int tx = tid & 31, ty = tid >> 5;
#pragma unroll
    for (int i = 0; i < 32; i += 8)
      tt[ty + i][tx] = src[(size_t)(r0 + ty + i) * C + c0 + tx];
    __syncthreads();
#pragma unroll
    for (int i = 0; i < 32; i += 8)
      dst[(size_t)(c0 + ty + i) * R + r0 + tx] = (__bf16)tt[tx][ty + i];
  } else if (bid < 6784) {       // Wv pack: Wv_b[l][j][m] = wqkv[l][j][1024+m]
    int e0 = ((bid - 6528) * 256 + tid) * 8;
    int l = e0 >> 18, rem = e0 & 262143;
    int m = rem >> 9, k = rem & 511;
    const float* s = wqkv + (size_t)l * 786432 + (size_t)m * 1536 + 1024 + k;
#pragma unroll
    for (int j = 0; j < 8; ++j) Wv_b[e0 + j] = (__bf16)s[j];
  } else if (bid < 6800) {       // y -> bf16
    int e0 = ((bid - 6784) * 256 + tid) * 8;
#pragma unroll
    for (int j = 0; j < 8; ++j) y_b[e0 + j] = (__bf16)y[e0 + j];
  } else {                       // beff[l] = bv @ wo + bo
    int b2 = bid - 6800;
    int l = b2 >> 1;
    int n = (b2 & 1) * 256 + tid;
    const float* bv = bqkv + l * 1536 + 1024;
    const float* w  = wo + (size_t)l * 262144;
    float s = bo[l * 512 + n];
#pragma unroll 8
    for (int k = 0; k < 512; ++k) s += bv[k] * w[(size_t)k * 512 + n];
    beff[l * 512 + n] = s;
  }
}

// ---------------- fence-free grid barrier (relaxed atomics only; no L2 inv/wb) ----------------
__device__ __forceinline__ void gridbar(int* cnt, int target) {
  asm volatile("s_waitcnt vmcnt(0)" ::: "memory");
  __syncthreads();
  if (threadIdx.x == 0) {
    __hip_atomic_fetch_add(cnt, 1, __ATOMIC_RELAXED, __HIP_MEMORY_SCOPE_AGENT);
    while (__hip_atomic_load(cnt, __ATOMIC_RELAXED, __HIP_MEMORY_SCOPE_AGENT) < target)
      __builtin_amdgcn_s_sleep(2);
  }
  __syncthreads();
  asm volatile("" ::: "memory");
}

// ---------------- LN row stats (row = tid>>3, 8 threads/row) ----------------
template<int NT, bool COHA>
__device__ __forceinline__ void ln_stats(const __bf16* A, int bm0, float& mu, float& rsg) {
  const int K = NT * 64;
  const int tid = threadIdx.x;
  const int row = tid >> 3, j8 = tid & 7;
  const __bf16* ap = A + (size_t)(bm0 + row) * K + j8 * (K / 8);
  float s = 0.f, s2 = 0.f;
#pragma unroll
  for (int i = 0; i < K / 8; i += 4) {
    bf16x4 v;
    if (COHA) v = __builtin_bit_cast(bf16x4, cload8(ap + i));
    else      v = *(const bf16x4*)(ap + i);
#pragma unroll
    for (int j = 0; j < 4; ++j) { float f = (float)v[j]; s += f; s2 += f * f; }
  }
  s  += __shfl_xor(s, 1);  s2 += __shfl_xor(s2, 1);
  s  += __shfl_xor(s, 2);  s2 += __shfl_xor(s2, 2);
  s  += __shfl_xor(s, 4);  s2 += __shfl_xor(s2, 4);
  mu = s / (float)K;
  rsg = rsqrtf(s2 / (float)K - mu * mu + 1e-5f);
}

// ---------------- 32x32-tile fused GEMM, depth-4 register pipeline ----------------
// out = epi( [LN(A)] @ Bt^T ); A: Mx(NT*64) row-major, Bt: Nx(NT*64) row-major.
// LNMODE: 0 none, 1 compute stats, 2 use mu_in/rs_in. resid/accum/outf stride 512.
template<int NT, int LNMODE, bool GELU, bool COHA, bool BIAS, bool RESID,
         bool ACCUM, bool OUTF, bool OUTB, bool COHO>
__device__ __forceinline__ void gemm32(
    const __bf16* A, const __bf16* Bt, int bm0, int bn0,
    const float* lng, const float* lnb, const float* bias,
    const float* resid, const float* accum, float* outf, __bf16* outb, int ldo,
    __bf16* AL, __bf16* BL, float mu_in = 0.f, float rs_in = 0.f)
{
  const int tid = threadIdx.x;
  constexpr int K = NT * 64;
  const int row = tid >> 3;
  const int kcol = (tid & 7) * 8;

  float mu = mu_in, rsg = rs_in;
  if (LNMODE == 1) ln_stats<NT, COHA>(A, bm0, mu, rsg);

  const __bf16* Ab0 = A + (size_t)(bm0 + row) * K + kcol;
  const __bf16* Bb0 = Bt + (size_t)(bn0 + row) * K + kcol;

  u64 ra0[4], ra1[4], rb0[4], rb1[4];
  auto issue = [&](int t, int s) {
    const __bf16* ap = Ab0 + t * 64;
    const __bf16* bp = Bb0 + t * 64;
    if (COHA) { ra0[s] = cload8(ap); ra1[s] = cload8(ap + 4); }
    else      { ra0[s] = *(const u64*)ap; ra1[s] = *(const u64*)(ap + 4); }
    rb0[s] = *(const u64*)bp; rb1[s] = *(const u64*)(bp + 4);
  };
#pragma unroll
  for (int s = 0; s < 4; ++s) issue(s, s);

  f32x4 acc = {0.f, 0.f, 0.f, 0.f};
  const int wave = tid >> 6, lane = tid & 63;
  const int wr = (wave >> 1) * 16, wc = (wave & 1) * 16;
  const int lr = lane & 15, lk8 = (lane >> 4) * 8;

  for (int ttc = 0; ttc < NT / 4; ++ttc) {
#pragma unroll
    for (int ti = 0; ti < 4; ++ti) {
      const int t = ttc * 4 + ti;
      bf16x4 lo = __builtin_bit_cast(bf16x4, ra0[ti]);
      bf16x4 hi = __builtin_bit_cast(bf16x4, ra1[ti]);
      if (LNMODE != 0) {
        const int kb = t * 64 + kcol;
        f32x4 g0 = *(const f32x4*)(lng + kb);
        f32x4 g1 = *(const f32x4*)(lng + kb + 4);
        f32x4 b0 = *(const f32x4*)(lnb + kb);
        f32x4 b1 = *(const f32x4*)(lnb + kb + 4);
#pragma unroll
        for (int j = 0; j < 4; ++j) {
          lo[j] = (__bf16)(((float)lo[j] - mu) * rsg * g0[j] + b0[j]);
          hi[j] = (__bf16)(((float)hi[j] - mu) * rsg * g1[j] + b1[j]);
        }
      }
      __bf16* al = AL + (ti & 1) * 2304 + row * 72 + kcol;
      __bf16* bl = BL + (ti & 1) * 2304 + row * 72 + kcol;
      *(bf16x4*)al = lo; *(bf16x4*)(al + 4) = hi;
      *(bf16x4*)bl = __builtin_bit_cast(bf16x4, rb0[ti]);
      *(bf16x4*)(bl + 4) = __builtin_bit_cast(bf16x4, rb1[ti]);
      __syncthreads();
      if (t + 4 < NT) issue(t + 4, ti);
      const __bf16* Ar = AL + (ti & 1) * 2304 + (wr + lr) * 72;
      const __bf16* Br = BL + (ti & 1) * 2304 + (wc + lr) * 72;
      bf16x8 a0 = *(const bf16x8*)(Ar + lk8);
      bf16x8 b0v = *(const bf16x8*)(Br + lk8);
      acc = __builtin_amdgcn_mfma_f32_16x16x32_bf16(a0, b0v, acc, 0, 0, 0);
      bf16x8 a1 = *(const bf16x8*)(Ar + 32 + lk8);
      bf16x8 b1v = *(const bf16x8*)(Br + 32 + lk8);
      acc = __builtin_amdgcn_mfma_f32_16x16x32_bf16(a1, b1v, acc, 0, 0, 0);
      __syncthreads();
    }
  }

  const int er = bm0 + wr + (lane >> 4) * 4;
  const int ec = bn0 + wc + lr;
#pragma unroll
  for (int e = 0; e < 4; ++e) {
    const int r = er + e;
    float v = acc[e];
    if (BIAS)  v += bias[ec];
    if (RESID) v += resid[r * 512 + ec];
    if (GELU)  v = gelu_f(v);
    if (ACCUM) v += accum[r * 512 + ec];
    if (OUTF)  outf[r * 512 + ec] = v;
    if (OUTB) {
      __bf16 h = (__bf16)v;
      if (COHO) cstore_bf16(outb + (size_t)r * ldo + ec, h);
      else      outb[(size_t)r * ldo + ec] = h;
    }
  }
}

// ---------------- aux: Weff GEMMs + projections (one-shot, normal caching) ----------------
__global__ __launch_bounds__(256) void aux_kernel(
    const __bf16* __restrict__ woT, const __bf16* __restrict__ Wv_b,
    const __bf16* __restrict__ xp_b, const __bf16* __restrict__ y_b,
    const __bf16* __restrict__ WpiT, const __bf16* __restrict__ WpaT,
    const float* __restrict__ bpi, const float* __restrict__ bpa,
    __bf16* __restrict__ WeffT, __bf16* __restrict__ xy_b)
{
  __shared__ __bf16 AL[2 * 32 * 72];
  __shared__ __bf16 BL[2 * 32 * 72];
  int bid = blockIdx.x;
  if (bid < 512) {        // WeffT[l][n][j] = sum_m woT[l][n][m] * Wv_b[l][j][m]
    int l = bid >> 8, t = bid & 255;
    gemm32<8,0,0,0,0,0,0,0,1,0>(woT + l * 262144, Wv_b + l * 262144,
        (t >> 4) * 32, (t & 15) * 32, nullptr, nullptr, nullptr,
        nullptr, nullptr, nullptr, WeffT + l * 262144, 512, AL, BL);
  } else if (bid < 576) { // xy[:, :512] = xp @ Wpi + bpi
    int t = bid - 512;
    gemm32<16,0,0,0,1,0,0,0,1,0>(xp_b, WpiT, (t >> 4) * 32, (t & 15) * 32,
        nullptr, nullptr, bpi, nullptr, nullptr, nullptr, xy_b, 1024, AL, BL);
  } else {                // xy[:, 512:] = y @ Wpa + bpa
    int t = bid - 576;
    gemm32<4,0,0,0,1,0,0,0,1,0>(y_b, WpaT, (t >> 4) * 32, (t & 15) * 32,
        nullptr, nullptr, bpa, nullptr, nullptr, nullptr, xy_b + 512, 1024, AL, BL);
  }
}

// ---------------- persistent mega kernel: base + 6-rec chain ----------------
__global__ __launch_bounds__(256) void mega_kernel(
    const __bf16* __restrict__ xy_b, const __bf16* __restrict__ WcabT,
    const __bf16* __restrict__ WccT, const __bf16* __restrict__ WeffT,
    const __bf16* __restrict__ w1T, const __bf16* __restrict__ w2T,
    const float* __restrict__ bc, const float* __restrict__ beff,
    const float* __restrict__ ln1g, const float* __restrict__ ln1b,
    const float* __restrict__ ln2g, const float* __restrict__ ln2b,
    const float* __restrict__ b1f, const float* __restrict__ b2f,
    float* base_f, float* c_f, __bf16* c_b, float* x_f,
    __bf16* xb2, __bf16* xb4, __bf16* u_b, float* z_f, __bf16* z_b,
    float* out, int* bcnt)
{
  __shared__ __bf16 AL[2 * 32 * 72];
  __shared__ __bf16 BL[2 * 32 * 72];
  const int wg = blockIdx.x;
  const int xcd = wg & 7, slot = wg >> 3;
  const int bm = (slot & 3) * 32;
  const int bn = (((xcd << 1) | (slot >> 2))) * 32;
  int bar = 0;

  // base = xy @ Wcab + bc  (writes f32 base + coherent bf16 c_b for r=0)
  gemm32<16,0,0,0,1,0,0,1,1,1>(xy_b, WcabT, bm, bn, nullptr, nullptr, bc,
      nullptr, nullptr, base_f, c_b, 512, AL, BL);
  gridbar(bcnt, bar += NWG);

  for (int r = 0; r < 6; ++r) {
    if (r > 0) {  // S1: c = base + z @ Wcc
      gemm32<8,0,0,1,0,1,0,1,1,1>(z_b, WccT, bm, bn, nullptr, nullptr, nullptr,
          base_f, nullptr, c_f, c_b, 512, AL, BL);
      gridbar(bcnt, bar += NWG);
    }
    for (int l = 0; l < 2; ++l) {
      const __bf16* Ain = (l == 0) ? c_b : xb4;
      const float*  Rin = (l == 0) ? ((r > 0) ? c_f : base_f) : x_f;
      // S2: x = resid + LN1(A) @ Weff + beff
      gemm32<8,1,0,1,1,1,0,1,1,1>(Ain, WeffT + l * 262144, bm, bn,
          ln1g + l * 512, ln1b + l * 512, beff + l * 512, Rin, nullptr,
          x_f, xb2, 512, AL, BL);
      gridbar(bcnt, bar += NWG);
      // S3: u = gelu(LN2(x) @ w1 + b1)  — stats once, 4 n-tiles per WG
      {
        float mu, rsg;
        ln_stats<8, true>(xb2, bm, mu, rsg);
        for (int i = 0; i < 4; ++i) {
          int n3 = (xcd << 3) | ((slot >> 2) << 2) | i;
          gemm32<8,2,1,1,1,0,0,0,1,1>(xb2, w1T + l * 1048576, bm, n3 * 32,
              ln2g + l * 512, ln2b + l * 512, b1f + l * 2048, nullptr, nullptr,
              nullptr, u_b, 2048, AL, BL, mu, rsg);
        }
      }
      gridbar(bcnt, bar += NWG);
      // S4: x = x + u @ w2 + b2 ; layer 1 accumulates into z (r=5 -> d_out)
      if (l == 0) {
        gemm32<32,0,0,1,1,1,0,1,1,1>(u_b, w2T, bm, bn, nullptr, nullptr, b2f,
            x_f, nullptr, x_f, xb4, 512, AL, BL);
        gridbar(bcnt, bar += NWG);
      } else {
        if (r == 0) {
          gemm32<32,0,0,1,1,1,0,1,1,1>(u_b, w2T + 1048576, bm, bn, nullptr, nullptr,
              b2f + 512, x_f, nullptr, z_f, z_b, 512, AL, BL);
        } else if (r < 5) {
          gemm32<32,0,0,1,1,1,1,1,1,1>(u_b, w2T + 1048576, bm, bn, nullptr, nullptr,
              b2f + 512, x_f, z_f, z_f, z_b, 512, AL, BL);
        } else {
          gemm32<32,0,0,1,1,1,1,1,0,0>(u_b, w2T + 1048576, bm, bn, nullptr, nullptr,
              b2f + 512, x_f, z_f, out, nullptr, 512, AL, BL);
        }
        if (r < 5) gridbar(bcnt, bar += NWG);
      }
    }
  }
}

extern "C" void kernel_launch(void* const* d_in, const int* in_sizes, int n_in,
                              void* d_out, int out_size, void* d_ws, size_t ws_size,
                              hipStream_t stream) {
  const float* x_encoded = (const float*)d_in[0];
  const float* y_current = (const float*)d_in[1];
  const float* Wpi  = (const float*)d_in[2];
  const float* bpi  = (const float*)d_in[3];
  const float* Wpa  = (const float*)d_in[4];
  const float* bpa  = (const float*)d_in[5];
  const float* Wc   = (const float*)d_in[6];
  const float* bc   = (const float*)d_in[7];
  const float* ln1g = (const float*)d_in[8];
  const float* ln1b = (const float*)d_in[9];
  const float* wqkv = (const float*)d_in[10];
  const float* bqkv = (const float*)d_in[11];
  const float* wo   = (const float*)d_in[12];
  const float* bo   = (const float*)d_in[13];
  const float* ln2g = (const float*)d_in[14];
  const float* ln2b = (const float*)d_in[15];
  const float* w1f  = (const float*)d_in[16];
  const float* b1f  = (const float*)d_in[17];
  const float* w2f  = (const float*)d_in[18];
  const float* b2f  = (const float*)d_in[19];
  (void)in_sizes; (void)n_in; (void)out_size; (void)ws_size;

  char* wsb = (char*)d_ws;
  size_t off = 0;
  auto carve = [&](size_t bytes) -> void* {
    void* p = wsb + off;
    off += (bytes + 255) & ~(size_t)255;
    return p;
  };
  __bf16* xp_b    = (__bf16*)carve(131072 * 2);
  __bf16* y_b     = (__bf16*)carve(32768 * 2);
  __bf16* WpiT    = (__bf16*)carve(524288 * 2);
  __bf16* WpaT    = (__bf16*)carve(131072 * 2);
  __bf16* WcabT   = (__bf16*)carve(524288 * 2);
  __bf16* WccT    = (__bf16*)carve(262144 * 2);
  __bf16* w1T     = (__bf16*)carve(2097152 * 2);
  __bf16* w2T     = (__bf16*)carve(2097152 * 2);
  __bf16* woT     = (__bf16*)carve(524288 * 2);
  __bf16* Wv_b    = (__bf16*)carve(524288 * 2);
  __bf16* WeffT   = (__bf16*)carve(524288 * 2);
  float*  beff    = (float*) carve(1024 * 4);
  __bf16* xy_b    = (__bf16*)carve(131072 * 2);
  float*  base_f  = (float*) carve(65536 * 4);
  float*  c_f     = (float*) carve(65536 * 4);
  __bf16* c_b     = (__bf16*)carve(65536 * 2);
  float*  x_f     = (float*) carve(65536 * 4);
  __bf16* xb2     = (__bf16*)carve(65536 * 2);
  __bf16* xb4     = (__bf16*)carve(65536 * 2);
  __bf16* u_b     = (__bf16*)carve(262144 * 2);
  float*  z_f     = (float*) carve(65536 * 4);
  __bf16* z_b     = (__bf16*)carve(65536 * 2);
  int*    d_bar   = (int*)   carve(256);

  hipMemsetAsync(d_bar, 0, 256, stream);
  prep_kernel<<<6804, 256, 0, stream>>>(x_encoded, Wpi, Wpa, Wc, w1f, w2f, wo,
      wqkv, y_current, bqkv, bo, xp_b, WpiT, WpaT, WcabT, WccT, w1T, w2T, woT,
      Wv_b, y_b, beff);
  aux_kernel<<<640, 256, 0, stream>>>(woT, Wv_b, xp_b, y_b, WpiT, WpaT,
      bpi, bpa, WeffT, xy_b);
  mega_kernel<<<NWG, 256, 0, stream>>>(
      xy_b, WcabT, WccT, WeffT, w1T, w2T, bc, beff,
      ln1g, ln1b, ln2g, ln2b, b1f, b2f,
      base_f, c_f, c_b, x_f, xb2, xb4, u_b, z_f, z_b,
      (float*)d_out, d_bar);
}

// Round 6
// 550.324 us; speedup vs baseline: 1.6789x; 1.0005x over previous
//
#include <hip/hip_runtime.h>
#include <math.h>

#define NWG 64

typedef __bf16 bf16x8 __attribute__((ext_vector_type(8)));
typedef __bf16 bf16x4 __attribute__((ext_vector_type(4)));
typedef float  f32x4  __attribute__((ext_vector_type(4)));
typedef unsigned long long u64;

__device__ __forceinline__ float gelu_f(float x) {
  const float k0 = 0.7978845608028654f;
  const float k1 = 0.044715f;
  float x3 = x * x * x;
  return 0.5f * x * (1.0f + tanhf(k0 * (x + k1 * x3)));
}

// coherent (agent-scope, IF$-backed) accessors: bypass non-coherent per-XCD L2
__device__ __forceinline__ u64 cload8(const void* p) {
  return __hip_atomic_load((u64*)p, __ATOMIC_RELAXED, __HIP_MEMORY_SCOPE_AGENT);
}
__device__ __forceinline__ void cstore_bf16(__bf16* p, __bf16 h) {
  __hip_atomic_store((short*)p, __builtin_bit_cast(short, h),
                     __ATOMIC_RELAXED, __HIP_MEMORY_SCOPE_AGENT);
}

// ---------------- prep: pool + weight transposes + Wv pack + y conv + beff ----------------
__global__ __launch_bounds__(256) void prep_kernel(
    const float* __restrict__ xe,
    const float* __restrict__ Wpi, const float* __restrict__ Wpa,
    const float* __restrict__ Wc,  const float* __restrict__ w1f,
    const float* __restrict__ w2f, const float* __restrict__ wo,
    const float* __restrict__ wqkv, const float* __restrict__ y,
    const float* __restrict__ bqkv, const float* __restrict__ bo,
    __bf16* __restrict__ xp_b,
    __bf16* __restrict__ WpiT, __bf16* __restrict__ WpaT,
    __bf16* __restrict__ WcabT, __bf16* __restrict__ WccT,
    __bf16* __restrict__ w1T,  __bf16* __restrict__ w2T,
    __bf16* __restrict__ woT,  __bf16* __restrict__ Wv_b,
    __bf16* __restrict__ y_b,  float* __restrict__ beff)
{
  int bid = blockIdx.x;
  int tid = threadIdx.x;
  if (bid < 512) {               // mean pool (128,512,1024) -> (128,1024) bf16
    int b = bid >> 2;
    int c = (bid & 3) * 256 + tid;
    const float* p = xe + (size_t)b * 512 * 1024 + c;
    float s = 0.f;
#pragma unroll 16
    for (int i = 0; i < 512; ++i) s += p[(size_t)i * 1024];
    xp_b[b * 1024 + c] = (__bf16)(s * (1.f / 512.f));
  } else if (bid < 6528) {       // transposes fp32 -> bf16 (N x K layout)
    int t = bid - 512;
    const float* src; __bf16* dst; int R, C;
    if      (t < 512)  {            src = Wpi;            dst = WpiT;          R = 1024; C = 512;  }
    else if (t < 640)  { t -= 512;  src = Wpa;            dst = WpaT;          R = 256;  C = 512;  }
    else if (t < 1152) { t -= 640;  src = Wc;             dst = WcabT;         R = 1024; C = 512;  }
    else if (t < 1408) { t -= 1152; src = Wc + 1024*512;  dst = WccT;          R = 512;  C = 512;  }
    else if (t < 2432) { t -= 1408; src = w1f;            dst = w1T;           R = 512;  C = 2048; }
    else if (t < 3456) { t -= 2432; src = w1f + 512*2048; dst = w1T + 1048576; R = 512;  C = 2048; }
    else if (t < 4480) { t -= 3456; src = w2f;            dst = w2T;           R = 2048; C = 512;  }
    else if (t < 5504) { t -= 4480; src = w2f + 2048*512; dst = w2T + 1048576; R = 2048; C = 512;  }
    else if (t < 5760) { t -= 5504; src = wo;             dst = woT;           R = 512;  C = 512;  }
    else               { t -= 5760; src = wo + 512*512;   dst = woT + 262144;  R = 512;  C = 512;  }
    int nbc = C / 32;
    int r0 = (t / nbc) * 32;
    int c0 = (t % nbc) * 32;
    __shared__ float tt[32][33];
    int tx = tid & 31, ty = tid >> 5;
#pragma unroll
    for (int i = 0; i < 32; i += 8)
      tt[ty + i][tx] = src[(size_t)(r0 + ty + i) * C + c0 + tx];
    __syncthreads();
#pragma unroll
    for (int i = 0; i < 32; i += 8)
      dst[(size_t)(c0 + ty + i) * R + r0 + tx] = (__bf16)tt[tx][ty + i];
  } else if (bid < 6784) {       // Wv pack: Wv_b[l][j][m] = wqkv[l][j][1024+m]
    int e0 = ((bid - 6528) * 256 + tid) * 8;
    int l = e0 >> 18, rem = e0 & 262143;
    int m = rem >> 9, k = rem & 511;
    const float* s = wqkv + (size_t)l * 786432 + (size_t)m * 1536 + 1024 + k;
#pragma unroll
    for (int j = 0; j < 8; ++j) Wv_b[e0 + j] = (__bf16)s[j];
  } else if (bid < 6800) {       // y -> bf16
    int e0 = ((bid - 6784) * 256 + tid) * 8;
#pragma unroll
    for (int j = 0; j < 8; ++j) y_b[e0 + j] = (__bf16)y[e0 + j];
  } else {                       // beff[l] = bv @ wo + bo
    int b2 = bid - 6800;
    int l = b2 >> 1;
    int n = (b2 & 1) * 256 + tid;
    const float* bv = bqkv + l * 1536 + 1024;
    const float* w  = wo + (size_t)l * 262144;
    float s = bo[l * 512 + n];
#pragma unroll 8
    for (int k = 0; k < 512; ++k) s += bv[k] * w[(size_t)k * 512 + n];
    beff[l * 512 + n] = s;
  }
}

// ---------------- fence-free grid barrier (relaxed atomics only; no L2 inv/wb) ----------------
__device__ __forceinline__ void gridbar(int* cnt, int target) {
  asm volatile("s_waitcnt vmcnt(0)" ::: "memory");
  __syncthreads();
  if (threadIdx.x == 0) {
    __hip_atomic_fetch_add(cnt, 1, __ATOMIC_RELAXED, __HIP_MEMORY_SCOPE_AGENT);
    while (__hip_atomic_load(cnt, __ATOMIC_RELAXED, __HIP_MEMORY_SCOPE_AGENT) < target)
      __builtin_amdgcn_s_sleep(2);
  }
  __syncthreads();
  asm volatile("" ::: "memory");
}

// ---------------- LN row stats (row = tid>>3, 8 threads/row) ----------------
template<int NT, bool COHA>
__device__ __forceinline__ void ln_stats(const __bf16* A, int bm0, float& mu, float& rsg) {
  const int K = NT * 64;
  const int tid = threadIdx.x;
  const int row = tid >> 3, j8 = tid & 7;
  const __bf16* ap = A + (size_t)(bm0 + row) * K + j8 * (K / 8);
  float s = 0.f, s2 = 0.f;
#pragma unroll
  for (int i = 0; i < K / 8; i += 4) {
    bf16x4 v;
    if (COHA) v = __builtin_bit_cast(bf16x4, cload8(ap + i));
    else      v = *(const bf16x4*)(ap + i);
#pragma unroll
    for (int j = 0; j < 4; ++j) { float f = (float)v[j]; s += f; s2 += f * f; }
  }
  s  += __shfl_xor(s, 1);  s2 += __shfl_xor(s2, 1);
  s  += __shfl_xor(s, 2);  s2 += __shfl_xor(s2, 2);
  s  += __shfl_xor(s, 4);  s2 += __shfl_xor(s2, 4);
  mu = s / (float)K;
  rsg = rsqrtf(s2 / (float)K - mu * mu + 1e-5f);
}

// ---------------- 32x32-tile fused GEMM, depth-4 register pipeline ----------------
// out = epi( [LN(A)] @ Bt^T ); A: Mx(NT*64) row-major, Bt: Nx(NT*64) row-major.
// LNMODE: 0 none, 1 compute stats, 2 use mu_in/rs_in. resid/accum/outf stride 512.
template<int NT, int LNMODE, bool GELU, bool COHA, bool BIAS, bool RESID,
         bool ACCUM, bool OUTF, bool OUTB, bool COHO>
__device__ __forceinline__ void gemm32(
    const __bf16* A, const __bf16* Bt, int bm0, int bn0,
    const float* lng, const float* lnb, const float* bias,
    const float* resid, const float* accum, float* outf, __bf16* outb, int ldo,
    __bf16* AL, __bf16* BL, float mu_in = 0.f, float rs_in = 0.f)
{
  const int tid = threadIdx.x;
  constexpr int K = NT * 64;
  const int row = tid >> 3;
  const int kcol = (tid & 7) * 8;

  float mu = mu_in, rsg = rs_in;
  if (LNMODE == 1) ln_stats<NT, COHA>(A, bm0, mu, rsg);

  const __bf16* Ab0 = A + (size_t)(bm0 + row) * K + kcol;
  const __bf16* Bb0 = Bt + (size_t)(bn0 + row) * K + kcol;

  u64 ra0[4], ra1[4], rb0[4], rb1[4];
  auto issue = [&](int t, int s) {
    const __bf16* ap = Ab0 + t * 64;
    const __bf16* bp = Bb0 + t * 64;
    if (COHA) { ra0[s] = cload8(ap); ra1[s] = cload8(ap + 4); }
    else      { ra0[s] = *(const u64*)ap; ra1[s] = *(const u64*)(ap + 4); }
    rb0[s] = *(const u64*)bp; rb1[s] = *(const u64*)(bp + 4);
  };
#pragma unroll
  for (int s = 0; s < 4; ++s) issue(s, s);

  f32x4 acc = {0.f, 0.f, 0.f, 0.f};
  const int wave = tid >> 6, lane = tid & 63;
  const int wr = (wave >> 1) * 16, wc = (wave & 1) * 16;
  const int lr = lane & 15, lk8 = (lane >> 4) * 8;

  for (int ttc = 0; ttc < NT / 4; ++ttc) {
#pragma unroll
    for (int ti = 0; ti < 4; ++ti) {
      const int t = ttc * 4 + ti;
      bf16x4 lo = __builtin_bit_cast(bf16x4, ra0[ti]);
      bf16x4 hi = __builtin_bit_cast(bf16x4, ra1[ti]);
      if (LNMODE != 0) {
        const int kb = t * 64 + kcol;
        f32x4 g0 = *(const f32x4*)(lng + kb);
        f32x4 g1 = *(const f32x4*)(lng + kb + 4);
        f32x4 b0 = *(const f32x4*)(lnb + kb);
        f32x4 b1 = *(const f32x4*)(lnb + kb + 4);
#pragma unroll
        for (int j = 0; j < 4; ++j) {
          lo[j] = (__bf16)(((float)lo[j] - mu) * rsg * g0[j] + b0[j]);
          hi[j] = (__bf16)(((float)hi[j] - mu) * rsg * g1[j] + b1[j]);
        }
      }
      __bf16* al = AL + (ti & 1) * 2304 + row * 72 + kcol;
      __bf16* bl = BL + (ti & 1) * 2304 + row * 72 + kcol;
      *(bf16x4*)al = lo; *(bf16x4*)(al + 4) = hi;
      *(bf16x4*)bl = __builtin_bit_cast(bf16x4, rb0[ti]);
      *(bf16x4*)(bl + 4) = __builtin_bit_cast(bf16x4, rb1[ti]);
      __syncthreads();
      if (t + 4 < NT) issue(t + 4, ti);
      const __bf16* Ar = AL + (ti & 1) * 2304 + (wr + lr) * 72;
      const __bf16* Br = BL + (ti & 1) * 2304 + (wc + lr) * 72;
      bf16x8 a0 = *(const bf16x8*)(Ar + lk8);
      bf16x8 b0v = *(const bf16x8*)(Br + lk8);
      acc = __builtin_amdgcn_mfma_f32_16x16x32_bf16(a0, b0v, acc, 0, 0, 0);
      bf16x8 a1 = *(const bf16x8*)(Ar + 32 + lk8);
      bf16x8 b1v = *(const bf16x8*)(Br + 32 + lk8);
      acc = __builtin_amdgcn_mfma_f32_16x16x32_bf16(a1, b1v, acc, 0, 0, 0);
      __syncthreads();
    }
  }

  const int er = bm0 + wr + (lane >> 4) * 4;
  const int ec = bn0 + wc + lr;
#pragma unroll
  for (int e = 0; e < 4; ++e) {
    const int r = er + e;
    float v = acc[e];
    if (BIAS)  v += bias[ec];
    if (RESID) v += resid[r * 512 + ec];
    if (GELU)  v = gelu_f(v);
    if (ACCUM) v += accum[r * 512 + ec];
    if (OUTF)  outf[r * 512 + ec] = v;
    if (OUTB) {
      __bf16 h = (__bf16)v;
      if (COHO) cstore_bf16(outb + (size_t)r * ldo + ec, h);
      else      outb[(size_t)r * ldo + ec] = h;
    }
  }
}

// ---------------- aux: Weff GEMMs + projections (one-shot, normal caching) ----------------
__global__ __launch_bounds__(256) void aux_kernel(
    const __bf16* __restrict__ woT, const __bf16* __restrict__ Wv_b,
    const __bf16* __restrict__ xp_b, const __bf16* __restrict__ y_b,
    const __bf16* __restrict__ WpiT, const __bf16* __restrict__ WpaT,
    const float* __restrict__ bpi, const float* __restrict__ bpa,
    __bf16* __restrict__ WeffT, __bf16* __restrict__ xy_b)
{
  __shared__ __bf16 AL[2 * 32 * 72];
  __shared__ __bf16 BL[2 * 32 * 72];
  int bid = blockIdx.x;
  if (bid < 512) {        // WeffT[l][n][j] = sum_m woT[l][n][m] * Wv_b[l][j][m]
    int l = bid >> 8, t = bid & 255;
    gemm32<8,0,0,0,0,0,0,0,1,0>(woT + l * 262144, Wv_b + l * 262144,
        (t >> 4) * 32, (t & 15) * 32, nullptr, nullptr, nullptr,
        nullptr, nullptr, nullptr, WeffT + l * 262144, 512, AL, BL);
  } else if (bid < 576) { // xy[:, :512] = xp @ Wpi + bpi
    int t = bid - 512;
    gemm32<16,0,0,0,1,0,0,0,1,0>(xp_b, WpiT, (t >> 4) * 32, (t & 15) * 32,
        nullptr, nullptr, bpi, nullptr, nullptr, nullptr, xy_b, 1024, AL, BL);
  } else {                // xy[:, 512:] = y @ Wpa + bpa
    int t = bid - 576;
    gemm32<4,0,0,0,1,0,0,0,1,0>(y_b, WpaT, (t >> 4) * 32, (t & 15) * 32,
        nullptr, nullptr, bpa, nullptr, nullptr, nullptr, xy_b + 512, 1024, AL, BL);
  }
}

// ---------------- persistent mega kernel: base + 6-rec chain ----------------
__global__ __launch_bounds__(256) void mega_kernel(
    const __bf16* __restrict__ xy_b, const __bf16* __restrict__ WcabT,
    const __bf16* __restrict__ WccT, const __bf16* __restrict__ WeffT,
    const __bf16* __restrict__ w1T, const __bf16* __restrict__ w2T,
    const float* __restrict__ bc, const float* __restrict__ beff,
    const float* __restrict__ ln1g, const float* __restrict__ ln1b,
    const float* __restrict__ ln2g, const float* __restrict__ ln2b,
    const float* __restrict__ b1f, const float* __restrict__ b2f,
    float* base_f, float* c_f, __bf16* c_b, float* x_f,
    __bf16* xb2, __bf16* xb4, __bf16* u_b, float* z_f, __bf16* z_b,
    float* out, int* bcnt)
{
  __shared__ __bf16 AL[2 * 32 * 72];
  __shared__ __bf16 BL[2 * 32 * 72];
  const int wg = blockIdx.x;
  const int xcd = wg & 7, slot = wg >> 3;
  const int bm = (slot & 3) * 32;
  const int bn = (((xcd << 1) | (slot >> 2))) * 32;
  int bar = 0;

  // base = xy @ Wcab + bc  (writes f32 base + coherent bf16 c_b for r=0)
  gemm32<16,0,0,0,1,0,0,1,1,1>(xy_b, WcabT, bm, bn, nullptr, nullptr, bc,
      nullptr, nullptr, base_f, c_b, 512, AL, BL);
  gridbar(bcnt, bar += NWG);

  for (int r = 0; r < 6; ++r) {
    if (r > 0) {  // S1: c = base + z @ Wcc
      gemm32<8,0,0,1,0,1,0,1,1,1>(z_b, WccT, bm, bn, nullptr, nullptr, nullptr,
          base_f, nullptr, c_f, c_b, 512, AL, BL);
      gridbar(bcnt, bar += NWG);
    }
    for (int l = 0; l < 2; ++l) {
      const __bf16* Ain = (l == 0) ? c_b : xb4;
      const float*  Rin = (l == 0) ? ((r > 0) ? c_f : base_f) : x_f;
      // S2: x = resid + LN1(A) @ Weff + beff
      gemm32<8,1,0,1,1,1,0,1,1,1>(Ain, WeffT + l * 262144, bm, bn,
          ln1g + l * 512, ln1b + l * 512, beff + l * 512, Rin, nullptr,
          x_f, xb2, 512, AL, BL);
      gridbar(bcnt, bar += NWG);
      // S3: u = gelu(LN2(x) @ w1 + b1)  — stats once, 4 n-tiles per WG
      {
        float mu, rsg;
        ln_stats<8, true>(xb2, bm, mu, rsg);
        for (int i = 0; i < 4; ++i) {
          int n3 = (xcd << 3) | ((slot >> 2) << 2) | i;
          gemm32<8,2,1,1,1,0,0,0,1,1>(xb2, w1T + l * 1048576, bm, n3 * 32,
              ln2g + l * 512, ln2b + l * 512, b1f + l * 2048, nullptr, nullptr,
              nullptr, u_b, 2048, AL, BL, mu, rsg);
        }
      }
      gridbar(bcnt, bar += NWG);
      // S4: x = x + u @ w2 + b2 ; layer 1 accumulates into z (r=5 -> d_out)
      if (l == 0) {
        gemm32<32,0,0,1,1,1,0,1,1,1>(u_b, w2T, bm, bn, nullptr, nullptr, b2f,
            x_f, nullptr, x_f, xb4, 512, AL, BL);
        gridbar(bcnt, bar += NWG);
      } else {
        if (r == 0) {
          gemm32<32,0,0,1,1,1,0,1,1,1>(u_b, w2T + 1048576, bm, bn, nullptr, nullptr,
              b2f + 512, x_f, nullptr, z_f, z_b, 512, AL, BL);
        } else if (r < 5) {
          gemm32<32,0,0,1,1,1,1,1,1,1>(u_b, w2T + 1048576, bm, bn, nullptr, nullptr,
              b2f + 512, x_f, z_f, z_f, z_b, 512, AL, BL);
        } else {
          gemm32<32,0,0,1,1,1,1,1,0,0>(u_b, w2T + 1048576, bm, bn, nullptr, nullptr,
              b2f + 512, x_f, z_f, out, nullptr, 512, AL, BL);
        }
        if (r < 5) gridbar(bcnt, bar += NWG);
      }
    }
  }
}

extern "C" void kernel_launch(void* const* d_in, const int* in_sizes, int n_in,
                              void* d_out, int out_size, void* d_ws, size_t ws_size,
                              hipStream_t stream) {
  const float* x_encoded = (const float*)d_in[0];
  const float* y_current = (const float*)d_in[1];
  const float* Wpi  = (const float*)d_in[2];
  const float* bpi  = (const float*)d_in[3];
  const float* Wpa  = (const float*)d_in[4];
  const float* bpa  = (const float*)d_in[5];
  const float* Wc   = (const float*)d_in[6];
  const float* bc   = (const float*)d_in[7];
  const float* ln1g = (const float*)d_in[8];
  const float* ln1b = (const float*)d_in[9];
  const float* wqkv = (const float*)d_in[10];
  const float* bqkv = (const float*)d_in[11];
  const float* wo   = (const float*)d_in[12];
  const float* bo   = (const float*)d_in[13];
  const float* ln2g = (const float*)d_in[14];
  const float* ln2b = (const float*)d_in[15];
  const float* w1f  = (const float*)d_in[16];
  const float* b1f  = (const float*)d_in[17];
  const float* w2f  = (const float*)d_in[18];
  const float* b2f  = (const float*)d_in[19];
  (void)in_sizes; (void)n_in; (void)out_size; (void)ws_size;

  char* wsb = (char*)d_ws;
  size_t off = 0;
  auto carve = [&](size_t bytes) -> void* {
    void* p = wsb + off;
    off += (bytes + 255) & ~(size_t)255;
    return p;
  };
  __bf16* xp_b    = (__bf16*)carve(131072 * 2);
  __bf16* y_b     = (__bf16*)carve(32768 * 2);
  __bf16* WpiT    = (__bf16*)carve(524288 * 2);
  __bf16* WpaT    = (__bf16*)carve(131072 * 2);
  __bf16* WcabT   = (__bf16*)carve(524288 * 2);
  __bf16* WccT    = (__bf16*)carve(262144 * 2);
  __bf16* w1T     = (__bf16*)carve(2097152 * 2);
  __bf16* w2T     = (__bf16*)carve(2097152 * 2);
  __bf16* woT     = (__bf16*)carve(524288 * 2);
  __bf16* Wv_b    = (__bf16*)carve(524288 * 2);
  __bf16* WeffT   = (__bf16*)carve(524288 * 2);
  float*  beff    = (float*) carve(1024 * 4);
  __bf16* xy_b    = (__bf16*)carve(131072 * 2);
  float*  base_f  = (float*) carve(65536 * 4);
  float*  c_f     = (float*) carve(65536 * 4);
  __bf16* c_b     = (__bf16*)carve(65536 * 2);
  float*  x_f     = (float*) carve(65536 * 4);
  __bf16* xb2     = (__bf16*)carve(65536 * 2);
  __bf16* xb4     = (__bf16*)carve(65536 * 2);
  __bf16* u_b     = (__bf16*)carve(262144 * 2);
  float*  z_f     = (float*) carve(65536 * 4);
  __bf16* z_b     = (__bf16*)carve(65536 * 2);
  int*    d_bar   = (int*)   carve(256);

  hipMemsetAsync(d_bar, 0, 256, stream);
  prep_kernel<<<6804, 256, 0, stream>>>(x_encoded, Wpi, Wpa, Wc, w1f, w2f, wo,
      wqkv, y_current, bqkv, bo, xp_b, WpiT, WpaT, WcabT, WccT, w1T, w2T, woT,
      Wv_b, y_b, beff);
  aux_kernel<<<640, 256, 0, stream>>>(woT, Wv_b, xp_b, y_b, WpiT, WpaT,
      bpi, bpa, WeffT, xy_b);
  mega_kernel<<<NWG, 256, 0, stream>>>(
      xy_b, WcabT, WccT, WeffT, w1T, w2T, bc, beff,
      ln1g, ln1b, ln2g, ln2b, b1f, b2f,
      base_f, c_f, c_b, x_f, xb2, xb4, u_b, z_f, z_b,
      (float*)d_out, d_bar);
}